// Round 2
// baseline (545.083 us; speedup 1.0000x reference)
//
#include <hip/hip_runtime.h>
#include <stdint.h>

#define IN_DIM 8192
#define OUT_DIM 4096
#define NNZ 1638400
#define BATCH 4096

typedef __bf16 bf16x8 __attribute__((ext_vector_type(8)));
typedef float f32x4 __attribute__((ext_vector_type(4)));
typedef short s16x2 __attribute__((ext_vector_type(2)));

// ---- helpers ----------------------------------------------------------------

__device__ __forceinline__ unsigned short f2bf(float f) {
  union { float f; unsigned int u; } v; v.f = f;
  unsigned int u = v.u;
  unsigned int r = (u + 0x7FFFu + ((u >> 16) & 1u)) >> 16;  // RNE
  return (unsigned short)r;
}

__device__ __forceinline__ void async16(const void* g, void* l) {
  __builtin_amdgcn_global_load_lds(
      (const __attribute__((address_space(1))) unsigned int*)g,
      (__attribute__((address_space(3))) unsigned int*)l,
      16, 0, 0);
}

__device__ __forceinline__ void convert_body(int i, const float* __restrict__ src,
                                             unsigned short* __restrict__ dst) {
  const float4* s = (const float4*)src;
  float4 a = s[2 * i];
  float4 b = s[2 * i + 1];
  union { unsigned short us[8]; uint4 v; } o;
  o.us[0] = f2bf(a.x); o.us[1] = f2bf(a.y); o.us[2] = f2bf(a.z); o.us[3] = f2bf(a.w);
  o.us[4] = f2bf(b.x); o.us[5] = f2bf(b.y); o.us[6] = f2bf(b.z); o.us[7] = f2bf(b.w);
  ((uint4*)dst)[i] = o.v;
}

// ---- kernel 1: zero W_bf16 (64 MiB of stores, ~15 us; must finish before ----
// any scatter atomic -> stream order provides that) ---------------------------

#define ZERO_BLOCKS ((IN_DIM * OUT_DIM) / 8 / 256)  // 16384

__global__ void zero_kernel(uint4* __restrict__ W) {
  W[blockIdx.x * 256 + threadIdx.x] = make_uint4(0, 0, 0, 0);
}

// ---- kernel 2: fused x-convert + scatter ------------------------------------
// Convert is 192 MiB of streaming traffic (~50 us). The 1.6M fire-and-forget
// pk_add_bf16 atomics issue from the first 1600 blocks and their latency
// hides under the stream -> scatter becomes ~free instead of a serial kernel.

#if defined(__has_builtin)
#  if __has_builtin(__builtin_amdgcn_global_atomic_fadd_v2bf16)
#    define HAVE_PK_BF16 1
#  endif
#endif

__device__ __forceinline__ void scat1(int c, int r, float w,
                                      unsigned int* __restrict__ W) {
  size_t e = (size_t)c * IN_DIM + r;     // element index in W^T [OUT][IN]
  const bool hi = (e & 1);
  unsigned short nb = f2bf(w);
#ifdef HAVE_PK_BF16
  s16x2 v;
  v.x = hi ? (short)0 : (short)nb;
  v.y = hi ? (short)nb : (short)0;
  __builtin_amdgcn_global_atomic_fadd_v2bf16(
      (__attribute__((address_space(1))) s16x2*)(W + (e >> 1)), v);
#else
  unsigned int* p = W + (e >> 1);
  unsigned int nw0 = hi ? ((unsigned int)nb << 16) : (unsigned int)nb;
  unsigned int cur = atomicCAS(p, 0u, nw0);
  if (cur == 0u) return;
  unsigned int assumed;
  do {
    assumed = cur;
    unsigned short h = hi ? (unsigned short)(assumed >> 16)
                          : (unsigned short)(assumed & 0xFFFFu);
    union { unsigned int u; float f; } hv; hv.u = (unsigned int)h << 16;
    unsigned short b2 = f2bf(hv.f + w);
    unsigned int nw = hi ? ((assumed & 0x0000FFFFu) | ((unsigned int)b2 << 16))
                         : ((assumed & 0xFFFF0000u) | (unsigned int)b2);
    cur = atomicCAS(p, assumed, nw);
  } while (cur != assumed);
#endif
}

__global__ void conv_scat_kernel(const float* __restrict__ x,
                                 unsigned short* __restrict__ x_bf16,
                                 const int4* __restrict__ ri4,
                                 const int4* __restrict__ ci4,
                                 const float4* __restrict__ w4,
                                 unsigned int* __restrict__ W) {
  int i = blockIdx.x * 256 + threadIdx.x;
  convert_body(i, x, x_bf16);
  if (i < NNZ / 4) {
    int4 r = ri4[i];
    int4 c = ci4[i];
    float4 w = w4[i];
    scat1(c.x, r.x, w.x, W);
    scat1(c.y, r.y, w.y, W);
    scat1(c.z, r.z, w.z, W);
    scat1(c.w, r.w, w.w, W);
  }
}

// ---- kernel 3: bf16 GEMM, 256x256 tile, 8 waves, B-first split staging ------
// C[M,N] = A[M,K] * Bt[N,K]^T + bias.
// Staging order per K-tile: 4 B-loads then 4 A-loads (per thread). Phase 3
// drains B of tile k+1 with vmcnt(2) (A still in flight) and prefetches the
// 8 B-fragments under the MFMA shadow; phase 0 waits only on A (vmcnt(0),
// true dep) and reads just 4 A-frags. Removes the per-K-tile 12-read dry
// lump that capped MfmaUtil at 48%.

#define TBM 256
#define TBN 256
#define TBK 64
#define NKT (IN_DIM / TBK)  // 128

__global__ __launch_bounds__(512, 2) void gemm_kernel(
    const unsigned short* __restrict__ A,   // [BATCH][IN_DIM] bf16 bits
    const unsigned short* __restrict__ Bt,  // [OUT_DIM][IN_DIM] bf16 bits
    const float* __restrict__ bias,         // [OUT_DIM]
    float* __restrict__ C) {                // [BATCH][OUT_DIM] fp32
  extern __shared__ __align__(16) unsigned short lds[];  // 131072 B

  const int tid = threadIdx.x;

  // bijective XCD swizzle: 256 workgroups, 8 XCDs, 32 each.
  const int bid = blockIdx.x;
  const int swz = ((bid & 7) << 5) | (bid >> 3);
  const int m0 = (swz & 15) * TBM;
  const int n0 = (swz >> 4) * TBN;

  const int wid = tid >> 6;
  const int lane = tid & 63;
  const int wm = wid >> 2;       // 0..1
  const int wn = wid & 3;        // 0..3
  const int quad = lane >> 4;
  const int lm = lane & 15;
  const int xorv = lm & 7;

  const unsigned short* Ab = A + (size_t)m0 * IN_DIM;
  const unsigned short* Bb = Bt + (size_t)n0 * IN_DIM;

  // staging geometry: tile = 256 rows x 8 segs of 16B; 512 thr -> 4 rounds.
  int soff[4], ldst[4];
#pragma unroll
  for (int c = 0; c < 4; ++c) {
    const int t2 = c * 512 + tid;
    const int srow = t2 >> 3;
    const int sseg = (t2 & 7) ^ (srow & 7);   // stage-side swizzle
    soff[c] = srow * IN_DIM + sseg * 8;
    ldst[c] = t2 * 16;                         // LDS byte offset (linear dest)
  }

  f32x4 acc[8][4] = {};

#define STAGE_A(kt_, b_, c_)                                                   \
  async16(Ab + (size_t)soff[c_] + (kt_)*TBK,                                   \
          (char*)lds + (b_)*65536 + ldst[c_])
#define STAGE_B(kt_, b_, c_)                                                   \
  async16(Bb + (size_t)soff[c_] + (kt_)*TBK,                                   \
          (char*)lds + (b_)*65536 + 32768 + ldst[c_])

#define RD_AF(lA_, q_)                                                         \
  do {                                                                         \
    _Pragma("unroll") for (int i = 0; i < 2; ++i) {                            \
      const int row = wm * 128 + ((q_)*2 + i) * 16 + lm;                       \
      _Pragma("unroll") for (int ss = 0; ss < 2; ++ss) {                       \
        const int p = ((ss << 2) | quad) ^ xorv;                               \
        af[i][ss] = *(const bf16x8*)((lA_) + row * TBK + p * 8);               \
      }                                                                        \
    }                                                                          \
  } while (0)

#define RD_BF(lB_, BFR)                                                        \
  do {                                                                         \
    _Pragma("unroll") for (int j = 0; j < 4; ++j) {                            \
      const int row = wn * 64 + j * 16 + lm;                                   \
      _Pragma("unroll") for (int ss = 0; ss < 2; ++ss) {                       \
        const int p = ((ss << 2) | quad) ^ xorv;                               \
        BFR[j][ss] = *(const bf16x8*)((lB_) + row * TBK + p * 8);              \
      }                                                                        \
    }                                                                          \
  } while (0)

#define MFMA_Q(q_, BFR)                                                        \
  do {                                                                         \
    __builtin_amdgcn_s_setprio(1);                                             \
    _Pragma("unroll") for (int i = 0; i < 2; ++i)                              \
    _Pragma("unroll") for (int j = 0; j < 4; ++j)                              \
    _Pragma("unroll") for (int ss = 0; ss < 2; ++ss)                           \
      acc[(q_)*2 + i][j] = __builtin_amdgcn_mfma_f32_16x16x32_bf16(            \
          af[i][ss], BFR[j][ss], acc[(q_)*2 + i][j], 0, 0, 0);                 \
    __builtin_amdgcn_s_setprio(0);                                             \
  } while (0)

// One K-tile. Entry: this tile's B already in BFRC regs; this tile's 4 A
// loads in flight (only outstanding VMEM). Stages tile kt+1 B-first; phase 3
// drains its B (vmcnt(2): 6 outstanding -> 4 oldest = B0-3 complete, in-order
// vmcnt semantics) and prefetches next B-frags into BFRN.
#define KT_BODY(kt_, buf_, BFRC, BFRN)                                         \
  do {                                                                         \
    const int nxt_ = (buf_) ^ 1;                                               \
    const int ktn_ = ((kt_) + 1) & (NKT - 1);                                  \
    const unsigned short* lA_ = lds + (buf_)*32768;                            \
    const unsigned short* lBn_ = lds + nxt_*32768 + 16384;                     \
    bf16x8 af[2][2];                                                           \
    /* phase 0: wait A (true dep), cross-wave barrier */                       \
    asm volatile("s_waitcnt vmcnt(0)" ::: "memory");                           \
    __builtin_amdgcn_sched_barrier(0);                                         \
    __builtin_amdgcn_s_barrier();                                              \
    RD_AF(lA_, 0);                                                             \
    STAGE_B(ktn_, nxt_, 0); STAGE_B(ktn_, nxt_, 1);                            \
    __builtin_amdgcn_s_barrier();                                              \
    MFMA_Q(0, BFRC);                                                           \
    __builtin_amdgcn_s_barrier();                                              \
    /* phase 1 */                                                              \
    RD_AF(lA_, 1);                                                             \
    STAGE_B(ktn_, nxt_, 2); STAGE_B(ktn_, nxt_, 3);                            \
    __builtin_amdgcn_s_barrier();                                              \
    MFMA_Q(1, BFRC);                                                           \
    __builtin_amdgcn_s_barrier();                                              \
    /* phase 2 */                                                              \
    RD_AF(lA_, 2);                                                             \
    STAGE_A(ktn_, nxt_, 0); STAGE_A(ktn_, nxt_, 1);                            \
    __builtin_amdgcn_s_barrier();                                              \
    MFMA_Q(2, BFRC);                                                           \
    __builtin_amdgcn_s_barrier();                                              \
    /* phase 3: drain next-B, prefetch next B-frags under MFMA shadow */       \
    asm volatile("s_waitcnt vmcnt(2)" ::: "memory");                           \
    __builtin_amdgcn_sched_barrier(0);                                         \
    __builtin_amdgcn_s_barrier();                                              \
    RD_AF(lA_, 3);                                                             \
    RD_BF(lBn_, BFRN);                                                         \
    STAGE_A(ktn_, nxt_, 2); STAGE_A(ktn_, nxt_, 3);                            \
    __builtin_amdgcn_s_barrier();                                              \
    MFMA_Q(3, BFRC);                                                           \
  } while (0)

  // prologue: stage K-tile 0, B-first, into buf 0; pre-read its B-frags.
#pragma unroll
  for (int c = 0; c < 4; ++c) STAGE_B(0, 0, c);
#pragma unroll
  for (int c = 0; c < 4; ++c) STAGE_A(0, 0, c);
  asm volatile("s_waitcnt vmcnt(4)" ::: "memory");  // B of tile 0 landed
  __builtin_amdgcn_sched_barrier(0);
  __builtin_amdgcn_s_barrier();
  bf16x8 bfrP[4][2], bfrQ[4][2];
  RD_BF(lds + 16384, bfrP);

  for (int kt = 0; kt < NKT; kt += 2) {
    KT_BODY(kt, 0, bfrP, bfrQ);
    KT_BODY(kt + 1, 1, bfrQ, bfrP);
  }

#undef KT_BODY
#undef MFMA_Q
#undef RD_BF
#undef RD_AF
#undef STAGE_B
#undef STAGE_A

  // Epilogue: C/D layout col = lane&15, row = quad*4 + reg  [m89-verified]
  const int ccol0 = n0 + wn * 64 + lm;
  const int crow0 = m0 + wm * 128;
#pragma unroll
  for (int j = 0; j < 4; ++j) {
    const int col = ccol0 + j * 16;
    const float bv = bias[col];
#pragma unroll
    for (int i = 0; i < 8; ++i) {
#pragma unroll
      for (int v = 0; v < 4; ++v) {
        const int row = crow0 + i * 16 + quad * 4 + v;
        C[(size_t)row * OUT_DIM + col] = acc[i][j][v] + bv;
      }
    }
  }
}

// ---- launch -----------------------------------------------------------------

extern "C" void kernel_launch(void* const* d_in, const int* in_sizes, int n_in,
                              void* d_out, int out_size, void* d_ws, size_t ws_size,
                              hipStream_t stream) {
  const float* x = (const float*)d_in[0];       // [4096][8192] fp32
  const int* row_idx = (const int*)d_in[1];     // [NNZ] int32
  const int* col_idx = (const int*)d_in[2];     // [NNZ] int32
  const float* weights = (const float*)d_in[3]; // [NNZ] fp32
  const float* bias = (const float*)d_in[4];    // [4096] fp32
  float* out = (float*)d_out;                   // [4096][4096] fp32

  // ws layout: W_bf16 [0,64M), x_bf16 [64M,128M).
  const size_t W_BF16_BYTES = (size_t)IN_DIM * OUT_DIM * 2;  // 64 MiB
  unsigned short* W_bf16 = (unsigned short*)d_ws;
  unsigned short* x_bf16 = (unsigned short*)((char*)d_ws + W_BF16_BYTES);

  static bool attr_set = false;
  if (!attr_set) {
    (void)hipFuncSetAttribute((const void*)gemm_kernel,
                              hipFuncAttributeMaxDynamicSharedMemorySize,
                              131072);
    attr_set = true;
  }

  // 1. zero W_bf16
  zero_kernel<<<ZERO_BLOCKS, 256, 0, stream>>>((uint4*)W_bf16);

  // 2. fused x->bf16 convert + scatter-add (atomics hide under stream)
  conv_scat_kernel<<<ZERO_BLOCKS, 256, 0, stream>>>(
      x, x_bf16, (const int4*)row_idx, (const int4*)col_idx,
      (const float4*)weights, (unsigned int*)W_bf16);

  // 3. GEMM + bias (256^2 tile, 8 waves, XCD-swizzled 1-D grid of 256)
  gemm_kernel<<<dim3(256), dim3(512), 131072, stream>>>(x_bf16, W_bf16, bias, out);
}